// Round 2
// baseline (531.152 us; speedup 1.0000x reference)
//
#include <hip/hip_runtime.h>
#include <stdint.h>

typedef __attribute__((ext_vector_type(8))) _Float16 half8;
typedef __attribute__((ext_vector_type(4))) _Float16 half4;
typedef __attribute__((ext_vector_type(4))) float f32x4;

// async global->LDS, 16B per lane; LDS dst must be wave-uniform-base + lane*16
__device__ __forceinline__ void gload_lds16(const void* g, void* l) {
  __builtin_amdgcn_global_load_lds(
      (const __attribute__((address_space(1))) void*)g,
      (__attribute__((address_space(3))) void*)l, 16, 0, 0);
}

// C[M,N] = epilogue(A[M,K] @ Bt[N,K]^T + bias)   (A,Bt fp16; bias fp32)
// EPI 0: leaky_relu(0.01) -> Ch fp16
// EPI 1: identity -> Cf fp32 (z out) AND Ch fp16 (z for VQ)
// EPI 2: sigmoid -> Cf fp32 (recon); accumulates sum((sig - Xref)^2) into lossAcc
template <int EPI>
__global__ __launch_bounds__(256, 2) void gemm_bt(
    const _Float16* __restrict__ A, const _Float16* __restrict__ Bt,
    const float* __restrict__ bias, _Float16* __restrict__ Ch,
    float* __restrict__ Cf, int M, int N, int Kd,
    const float* __restrict__ Xref, float* __restrict__ lossAcc) {
  __shared__ __align__(16) _Float16 As[128 * 32];
  __shared__ __align__(16) _Float16 Bs[128 * 32];
  __shared__ float red[256];

  const int tid = threadIdx.x;
  const int lane = tid & 63;
  const int wav = tid >> 6;
  const int m0 = blockIdx.y * 128;
  const int n0 = blockIdx.x * 128;
  const int wm = (wav >> 1) * 64;
  const int wn = (wav & 1) * 64;
  const int l15 = lane & 15;
  const int quad = lane >> 4;

  f32x4 acc[4][4];
#pragma unroll
  for (int i = 0; i < 4; i++)
#pragma unroll
    for (int j = 0; j < 4; j++) acc[i][j] = (f32x4){0.f, 0.f, 0.f, 0.f};

  const int ci0 = tid, ci1 = tid + 256;  // 16B chunk ids, wave-contiguous
  const int rA0 = ci0 >> 2, kA0 = (ci0 & 3) << 3;
  const int rA1 = ci1 >> 2, kA1 = (ci1 & 3) << 3;

  for (int kt = 0; kt < Kd; kt += 32) {
    __syncthreads();
    gload_lds16(A + (size_t)(m0 + rA0) * Kd + kt + kA0, &As[ci0 * 8]);
    gload_lds16(A + (size_t)(m0 + rA1) * Kd + kt + kA1, &As[ci1 * 8]);
    gload_lds16(Bt + (size_t)(n0 + rA0) * Kd + kt + kA0, &Bs[ci0 * 8]);
    gload_lds16(Bt + (size_t)(n0 + rA1) * Kd + kt + kA1, &Bs[ci1 * 8]);
    __syncthreads();

    half8 af[4], bq[4];
#pragma unroll
    for (int i = 0; i < 4; i++) {
      af[i] = *(const half8*)&As[(wm + i * 16 + l15) * 32 + quad * 8];
      bq[i] = *(const half8*)&Bs[(wn + i * 16 + l15) * 32 + quad * 8];
    }
#pragma unroll
    for (int mi = 0; mi < 4; mi++)
#pragma unroll
      for (int ni = 0; ni < 4; ni++)
        acc[mi][ni] = __builtin_amdgcn_mfma_f32_16x16x32_f16(af[mi], bq[ni],
                                                             acc[mi][ni], 0, 0, 0);
  }

  float lsum = 0.f;
#pragma unroll
  for (int ni = 0; ni < 4; ni++) {
    const int col = n0 + wn + ni * 16 + l15;
    const float bv = bias[col];
#pragma unroll
    for (int mi = 0; mi < 4; mi++) {
      const int row0 = m0 + wm + mi * 16 + quad * 4;
#pragma unroll
      for (int r = 0; r < 4; r++) {
        float v = acc[mi][ni][r] + bv;
        const size_t o = (size_t)(row0 + r) * N + col;
        if (EPI == 0) {
          v = v > 0.f ? v : 0.01f * v;
          Ch[o] = (_Float16)v;
        } else if (EPI == 1) {
          Cf[o] = v;
          Ch[o] = (_Float16)v;
        } else {
          float s = 1.f / (1.f + __expf(-v));
          Cf[o] = s;
          float d = s - Xref[o];
          lsum += d * d;
        }
      }
    }
  }
  if (EPI == 2) {
    red[tid] = lsum;
    __syncthreads();
    for (int s = 128; s > 0; s >>= 1) {
      if (tid < s) red[tid] += red[tid + s];
      __syncthreads();
    }
    if (tid == 0) atomicAdd(lossAcc, red[0]);
  }
}

// per 16-row group per wave: argmin_k (||E_k||^2 - 2 z.E_k) via fp16 MFMA;
// writes e = E[idx] (fp32 out + fp16 for decoder), accumulates sum of min
// squared distances (vq sum) into vq_acc.
__global__ __launch_bounds__(256, 4) void vq_argmin(
    const _Float16* __restrict__ zh, const _Float16* __restrict__ Eh,
    const float* __restrict__ E, const float* __restrict__ ek2,
    float* __restrict__ e_out, _Float16* __restrict__ eh_out,
    float* __restrict__ vq_acc) {
  __shared__ __align__(16) _Float16 Es[512 * 32];  // 32 KB codebook chunk
  __shared__ float ek2s[512];
  __shared__ float z2s[64];
  __shared__ int idxs[64];
  __shared__ float vred[256];

  const int tid = threadIdx.x;
  const int lane = tid & 63;
  const int wav = tid >> 6;
  const int l15 = lane & 15;
  const int quad = lane >> 4;
  const int rbase = blockIdx.x * 64 + wav * 16;

  const half8 zf = *(const half8*)(zh + ((size_t)(rbase + l15)) * 32 + quad * 8);

  float z2 = 0.f;
#pragma unroll
  for (int j = 0; j < 8; j++) {
    float v = (float)zf[j];
    z2 += v * v;
  }
  z2 += __shfl_xor(z2, 16);
  z2 += __shfl_xor(z2, 32);
  if (quad == 0) z2s[wav * 16 + l15] = z2;

  float best[4] = {1e30f, 1e30f, 1e30f, 1e30f};
  int bidx[4] = {0, 0, 0, 0};

  for (int cb = 0; cb < 2048; cb += 512) {
    __syncthreads();
#pragma unroll
    for (int j = 0; j < 8; j++) {
      int u = j * 256 + tid;
      *(half8*)&Es[u * 8] = *(const half8*)&Eh[(size_t)cb * 32 + u * 8];
    }
    ek2s[tid] = ek2[cb + tid];
    ek2s[tid + 256] = ek2[cb + tid + 256];
    __syncthreads();

    for (int c = 0; c < 512; c += 16) {
      const half8 ef = *(const half8*)&Es[(c + l15) * 32 + quad * 8];
      f32x4 d = (f32x4){0.f, 0.f, 0.f, 0.f};
      d = __builtin_amdgcn_mfma_f32_16x16x32_f16(zf, ef, d, 0, 0, 0);
      const float e2 = ek2s[c + l15];
      const int cg = cb + c + l15;
#pragma unroll
      for (int r = 0; r < 4; r++) {
        float dist = fmaf(-2.f, d[r], e2);
        if (dist < best[r]) { best[r] = dist; bidx[r] = cg; }  // first-min kept
      }
    }
  }

#pragma unroll
  for (int off = 1; off < 16; off <<= 1) {
#pragma unroll
    for (int r = 0; r < 4; r++) {
      float ov = __shfl_xor(best[r], off);
      int oi = __shfl_xor(bidx[r], off);
      if (ov < best[r] || (ov == best[r] && oi < bidx[r])) {
        best[r] = ov;
        bidx[r] = oi;
      }
    }
  }

  float vpart = 0.f;
  if (l15 == 0) {
#pragma unroll
    for (int r = 0; r < 4; r++) {
      idxs[wav * 16 + quad * 4 + r] = bidx[r];
      vpart += z2s[wav * 16 + quad * 4 + r] + best[r];
    }
  }
  vred[tid] = vpart;
  __syncthreads();
  for (int s = 128; s > 0; s >>= 1) {
    if (tid < s) vred[tid] += vred[tid + s];
    __syncthreads();
  }
  if (tid == 0) atomicAdd(vq_acc, vred[0]);

  // gather e rows: 64 rows x 128B fp32, 32B (8 floats) per thread
  const int rowb = tid >> 2, part = tid & 3;
  const int idx = idxs[rowb];
  const size_t orow = ((size_t)blockIdx.x * 64 + rowb) * 32 + part * 8;
  const f32x4 ea = *(const f32x4*)(E + (size_t)idx * 32 + part * 8);
  const f32x4 eb = *(const f32x4*)(E + (size_t)idx * 32 + part * 8 + 4);
  *(f32x4*)(e_out + orow) = ea;
  *(f32x4*)(e_out + orow + 4) = eb;
  half8 ehv;
#pragma unroll
  for (int j = 0; j < 4; j++) { ehv[j] = (_Float16)ea[j]; ehv[j + 4] = (_Float16)eb[j]; }
  *(half8*)(eh_out + orow) = ehv;
}

// W fp32 [K][N] -> Wt fp16 [N][K]
__global__ void transpose_conv(const float* __restrict__ W,
                               _Float16* __restrict__ Wt, int K, int N) {
  __shared__ float t[32][33];
  const int tx = threadIdx.x & 31, ty = threadIdx.x >> 5;
  const int bx = blockIdx.x * 32, by = blockIdx.y * 32;
#pragma unroll
  for (int i = 0; i < 32; i += 8)
    t[ty + i][tx] = W[(size_t)(by + ty + i) * N + bx + tx];
  __syncthreads();
#pragma unroll
  for (int i = 0; i < 32; i += 8)
    Wt[(size_t)(bx + ty + i) * K + by + tx] = (_Float16)t[tx][ty + i];
}

// x fp32 -> fp16, 4 elements/thread
__global__ void conv_x(const float* __restrict__ x, _Float16* __restrict__ xh) {
  const size_t i = (size_t)blockIdx.x * 256 + threadIdx.x;
  const f32x4 v = *(const f32x4*)(x + i * 4);
  half4 h;
#pragma unroll
  for (int j = 0; j < 4; j++) h[j] = (_Float16)v[j];
  *(half4*)(xh + i * 4) = h;
}

// E fp32 [2048][32] -> Eh fp16 + per-row squared norms (fp32)
__global__ void conv_E(const float* __restrict__ E, _Float16* __restrict__ Eh,
                       float* __restrict__ ek2) {
  const int c = blockIdx.x * 256 + threadIdx.x;
  float s = 0.f;
#pragma unroll
  for (int k = 0; k < 32; k++) {
    float v = E[(size_t)c * 32 + k];
    s += v * v;
    Eh[(size_t)c * 32 + k] = (_Float16)v;
  }
  ek2[c] = s;
}

__global__ void finalize_k(const float* __restrict__ scal, float* __restrict__ out) {
  const float vq = 1.25f * (scal[0] / 16384.f);  // (1+BETA) * mean
  const float rl = scal[1] / 16384.f;
  out[0] = rl + vq;
  out[1] = rl;
  out[2] = vq;
}

extern "C" void kernel_launch(void* const* d_in, const int* in_sizes, int n_in,
                              void* d_out, int out_size, void* d_ws, size_t ws_size,
                              hipStream_t stream) {
  const float* x = (const float*)d_in[0];
  const float* We1 = (const float*)d_in[1];
  const float* be1 = (const float*)d_in[2];
  const float* We2 = (const float*)d_in[3];
  const float* be2 = (const float*)d_in[4];
  const float* We3 = (const float*)d_in[5];
  const float* be3 = (const float*)d_in[6];
  const float* We4 = (const float*)d_in[7];
  const float* be4 = (const float*)d_in[8];
  const float* E = (const float*)d_in[9];
  const float* Wd1 = (const float*)d_in[10];
  const float* bd1 = (const float*)d_in[11];
  const float* Wd2 = (const float*)d_in[12];
  const float* bd2 = (const float*)d_in[13];
  const float* Wd3 = (const float*)d_in[14];
  const float* bd3 = (const float*)d_in[15];
  const float* Wd4 = (const float*)d_in[16];
  const float* bd4 = (const float*)d_in[17];

  float* out = (float*)d_out;
  char* ws = (char*)d_ws;

  size_t off = 0;
  auto alloc = [&](size_t bytes) {
    size_t r = off;
    off += (bytes + 255) & ~(size_t)255;
    return r;
  };
  const size_t oXH = alloc((size_t)16384 * 1024 * 2);
  const size_t oWT1 = alloc((size_t)1024 * 1024 * 2);
  const size_t oWT2 = alloc((size_t)512 * 1024 * 2);
  const size_t oWT3 = alloc((size_t)256 * 512 * 2);
  const size_t oWT4 = alloc((size_t)256 * 256 * 2);
  const size_t oWD1 = alloc((size_t)256 * 256 * 2);
  const size_t oWD2 = alloc((size_t)512 * 256 * 2);
  const size_t oWD3 = alloc((size_t)1024 * 512 * 2);
  const size_t oWD4 = alloc((size_t)1024 * 1024 * 2);
  const size_t oEH = alloc((size_t)2048 * 32 * 2);
  const size_t oEK2 = alloc((size_t)2048 * 4);
  const size_t oSC = alloc(256);
  const size_t oZH = alloc((size_t)16384 * 256 * 2);
  const size_t oQH = alloc((size_t)16384 * 256 * 2);
  const size_t oH1 = alloc((size_t)16384 * 1024 * 2);  // h1 / d3
  const size_t oH2 = alloc((size_t)16384 * 512 * 2);   // h2 / d2
  const size_t oH3 = alloc((size_t)16384 * 256 * 2);   // h3 / d1

  _Float16* xh = (_Float16*)(ws + oXH);
  _Float16* WT1 = (_Float16*)(ws + oWT1);
  _Float16* WT2 = (_Float16*)(ws + oWT2);
  _Float16* WT3 = (_Float16*)(ws + oWT3);
  _Float16* WT4 = (_Float16*)(ws + oWT4);
  _Float16* WD1 = (_Float16*)(ws + oWD1);
  _Float16* WD2 = (_Float16*)(ws + oWD2);
  _Float16* WD3 = (_Float16*)(ws + oWD3);
  _Float16* WD4 = (_Float16*)(ws + oWD4);
  _Float16* Eh = (_Float16*)(ws + oEH);
  float* ek2 = (float*)(ws + oEK2);
  float* scal = (float*)(ws + oSC);
  _Float16* zhw = (_Float16*)(ws + oZH);
  _Float16* qh = (_Float16*)(ws + oQH);
  _Float16* h1 = (_Float16*)(ws + oH1);
  _Float16* h2 = (_Float16*)(ws + oH2);
  _Float16* h3 = (_Float16*)(ws + oH3);

  float* zout = out;                            // [16384,256]
  float* eout = out + (size_t)16384 * 256;      // [16384,256]
  float* rout = out + (size_t)16384 * 256 * 2;  // [16384,1024]
  float* sout = rout + (size_t)16384 * 1024;    // 3 scalars

  hipMemsetAsync(ws + oSC, 0, 8, stream);

  dim3 blk(256);
  conv_x<<<16384, blk, 0, stream>>>(x, xh);
  transpose_conv<<<dim3(32, 32), blk, 0, stream>>>(We1, WT1, 1024, 1024);
  transpose_conv<<<dim3(16, 32), blk, 0, stream>>>(We2, WT2, 1024, 512);
  transpose_conv<<<dim3(8, 16), blk, 0, stream>>>(We3, WT3, 512, 256);
  transpose_conv<<<dim3(8, 8), blk, 0, stream>>>(We4, WT4, 256, 256);
  transpose_conv<<<dim3(8, 8), blk, 0, stream>>>(Wd1, WD1, 256, 256);
  transpose_conv<<<dim3(16, 8), blk, 0, stream>>>(Wd2, WD2, 256, 512);
  transpose_conv<<<dim3(32, 16), blk, 0, stream>>>(Wd3, WD3, 512, 1024);
  transpose_conv<<<dim3(32, 32), blk, 0, stream>>>(Wd4, WD4, 1024, 1024);
  conv_E<<<8, blk, 0, stream>>>(E, Eh, ek2);

  // encoder
  gemm_bt<0><<<dim3(8, 128), blk, 0, stream>>>(xh, WT1, be1, h1, nullptr, 16384,
                                               1024, 1024, nullptr, nullptr);
  gemm_bt<0><<<dim3(4, 128), blk, 0, stream>>>(h1, WT2, be2, h2, nullptr, 16384,
                                               512, 1024, nullptr, nullptr);
  gemm_bt<0><<<dim3(2, 128), blk, 0, stream>>>(h2, WT3, be3, h3, nullptr, 16384,
                                               256, 512, nullptr, nullptr);
  gemm_bt<1><<<dim3(2, 128), blk, 0, stream>>>(h3, WT4, be4, zhw, zout, 16384,
                                               256, 256, nullptr, nullptr);
  // vector quantizer
  vq_argmin<<<2048, blk, 0, stream>>>(zhw, Eh, E, ek2, eout, qh, &scal[0]);
  // decoder
  gemm_bt<0><<<dim3(2, 128), blk, 0, stream>>>(qh, WD1, bd1, h3, nullptr, 16384,
                                               256, 256, nullptr, nullptr);
  gemm_bt<0><<<dim3(4, 128), blk, 0, stream>>>(h3, WD2, bd2, h2, nullptr, 16384,
                                               512, 256, nullptr, nullptr);
  gemm_bt<0><<<dim3(8, 128), blk, 0, stream>>>(h2, WD3, bd3, h1, nullptr, 16384,
                                               1024, 512, nullptr, nullptr);
  gemm_bt<2><<<dim3(8, 128), blk, 0, stream>>>(h1, WD4, bd4, nullptr, rout, 16384,
                                               1024, 1024, x, &scal[1]);
  finalize_k<<<1, 1, 0, stream>>>(scal, sout);
}

// Round 3
// 490.975 us; speedup vs baseline: 1.0818x; 1.0818x over previous
//
#include <hip/hip_runtime.h>
#include <stdint.h>

typedef __attribute__((ext_vector_type(8))) _Float16 half8;
typedef __attribute__((ext_vector_type(4))) _Float16 half4;
typedef __attribute__((ext_vector_type(4))) float f32x4;

// async global->LDS, 16B per lane; LDS dst must be wave-uniform-base + lane*16
__device__ __forceinline__ void gload_lds16(const void* g, void* l) {
  __builtin_amdgcn_global_load_lds(
      (const __attribute__((address_space(1))) void*)g,
      (__attribute__((address_space(3))) void*)l, 16, 0, 0);
}

// C[M,N] = epilogue(A[M,K] @ Bt[N,K]^T + bias)   (A,Bt fp16; bias fp32)
// BK=64, XOR-swizzled LDS (chunk (row,c) stored at chunk col c^(row&7)),
// coalesced LDS-roundtrip epilogue.
// EPI 0: leaky_relu(0.01) -> Ch fp16
// EPI 1: identity -> Cf fp32 (z out) AND Ch fp16 (z for VQ)
// EPI 2: sigmoid -> Cf fp32 (recon); accumulates sum((sig - Xref)^2) into lossAcc
template <int EPI>
__global__ __launch_bounds__(256, 2) void gemm_bt(
    const _Float16* __restrict__ A, const _Float16* __restrict__ Bt,
    const float* __restrict__ bias, _Float16* __restrict__ Ch,
    float* __restrict__ Cf, int M, int N, int Kd,
    const float* __restrict__ Xref, float* __restrict__ lossAcc) {
  __shared__ __align__(16) _Float16 smem[2 * 128 * 64];  // As | Bs = 32 KB
  __shared__ float red[256];
  _Float16* As = smem;
  _Float16* Bs = smem + 128 * 64;

  const int tid = threadIdx.x;
  const int lane = tid & 63;
  const int wav = tid >> 6;
  const int m0 = blockIdx.y * 128;
  const int n0 = blockIdx.x * 128;
  const int wm = (wav >> 1) * 64;
  const int wn = (wav & 1) * 64;
  const int l15 = lane & 15;
  const int quad = lane >> 4;

  f32x4 acc[4][4];
#pragma unroll
  for (int i = 0; i < 4; i++)
#pragma unroll
    for (int j = 0; j < 4; j++) acc[i][j] = (f32x4){0.f, 0.f, 0.f, 0.f};

  // staging: 1024 16B-chunks per matrix per K-tile; chunk ci holds global
  // (row=ci>>3, kcol=((ci&7)^(row&7))*8)  -> bank-conflict-free frag reads
  int rowS[4], kS[4];
#pragma unroll
  for (int j = 0; j < 4; j++) {
    const int ci = j * 256 + tid;
    const int row = ci >> 3;
    rowS[j] = row;
    kS[j] = ((ci & 7) ^ (row & 7)) << 3;
  }

  for (int kt = 0; kt < Kd; kt += 64) {
    __syncthreads();
#pragma unroll
    for (int j = 0; j < 4; j++) {
      const int ci = j * 256 + tid;
      gload_lds16(A + (size_t)(m0 + rowS[j]) * Kd + kt + kS[j], &As[ci * 8]);
      gload_lds16(Bt + (size_t)(n0 + rowS[j]) * Kd + kt + kS[j], &Bs[ci * 8]);
    }
    __syncthreads();

#pragma unroll
    for (int s = 0; s < 2; s++) {
      half8 af[4], bq[4];
#pragma unroll
      for (int i = 0; i < 4; i++) {
        const int ra = wm + i * 16 + l15;
        const int ca = (s * 4 + quad) ^ (ra & 7);
        af[i] = *(const half8*)&As[ra * 64 + ca * 8];
        const int rb = wn + i * 16 + l15;
        const int cb = (s * 4 + quad) ^ (rb & 7);
        bq[i] = *(const half8*)&Bs[rb * 64 + cb * 8];
      }
#pragma unroll
      for (int mi = 0; mi < 4; mi++)
#pragma unroll
        for (int ni = 0; ni < 4; ni++)
          acc[mi][ni] = __builtin_amdgcn_mfma_f32_16x16x32_f16(af[mi], bq[ni],
                                                               acc[mi][ni], 0, 0, 0);
    }
  }

  // epilogue: two 64-row phases through LDS (reused as 64x128 fp32 = 32 KB)
  float lsum = 0.f;
  float* eb = (float*)smem;
#pragma unroll
  for (int p = 0; p < 2; p++) {
    __syncthreads();  // prior-phase reads / K-loop frag reads complete
    if ((wav >> 1) == p) {
#pragma unroll
      for (int mi = 0; mi < 4; mi++)
#pragma unroll
        for (int ni = 0; ni < 4; ni++)
#pragma unroll
          for (int r = 0; r < 4; r++) {
            const int rl = mi * 16 + quad * 4 + r;
            const int cl = wn + ni * 16 + l15;
            eb[rl * 128 + cl] = acc[mi][ni][r];
          }
    }
    __syncthreads();
#pragma unroll
    for (int j = 0; j < 8; j++) {
      const int c = j * 256 + tid;
      const int rl = c >> 5;
      const int cl = (c & 31) * 4;
      const f32x4 v = *(const f32x4*)&eb[rl * 128 + cl];
      const int gcol = n0 + cl;
      const f32x4 bv = *(const f32x4*)&bias[gcol];
      const size_t o = (size_t)(m0 + p * 64 + rl) * N + gcol;
      if (EPI == 0) {
        half4 h;
#pragma unroll
        for (int q = 0; q < 4; q++) {
          float t = v[q] + bv[q];
          t = t > 0.f ? t : 0.01f * t;
          h[q] = (_Float16)t;
        }
        *(half4*)&Ch[o] = h;
      } else if (EPI == 1) {
        f32x4 t;
        half4 h;
#pragma unroll
        for (int q = 0; q < 4; q++) {
          t[q] = v[q] + bv[q];
          h[q] = (_Float16)t[q];
        }
        *(f32x4*)&Cf[o] = t;
        *(half4*)&Ch[o] = h;
      } else {
        const f32x4 xr = *(const f32x4*)&Xref[o];
        f32x4 sv;
#pragma unroll
        for (int q = 0; q < 4; q++) {
          const float s = 1.f / (1.f + __expf(-(v[q] + bv[q])));
          sv[q] = s;
          const float d = s - xr[q];
          lsum += d * d;
        }
        *(f32x4*)&Cf[o] = sv;
      }
    }
  }
  if (EPI == 2) {
    __syncthreads();
    red[tid] = lsum;
    __syncthreads();
    for (int s = 128; s > 0; s >>= 1) {
      if (tid < s) red[tid] += red[tid + s];
      __syncthreads();
    }
    if (tid == 0) atomicAdd(lossAcc, red[0]);
  }
}

// per 16-row group per wave: argmin_k (||E_k||^2 - 2 z.E_k) via fp16 MFMA;
// writes e = E[idx] (fp32 out + fp16 for decoder), accumulates sum of min
// squared distances (vq sum) into vq_acc.
__global__ __launch_bounds__(256, 4) void vq_argmin(
    const _Float16* __restrict__ zh, const _Float16* __restrict__ Eh,
    const float* __restrict__ E, const float* __restrict__ ek2,
    float* __restrict__ e_out, _Float16* __restrict__ eh_out,
    float* __restrict__ vq_acc) {
  __shared__ __align__(16) _Float16 Es[512 * 32];  // 32 KB codebook chunk
  __shared__ float ek2s[512];
  __shared__ float z2s[64];
  __shared__ int idxs[64];
  __shared__ float vred[256];

  const int tid = threadIdx.x;
  const int lane = tid & 63;
  const int wav = tid >> 6;
  const int l15 = lane & 15;
  const int quad = lane >> 4;
  const int rbase = blockIdx.x * 64 + wav * 16;

  const half8 zf = *(const half8*)(zh + ((size_t)(rbase + l15)) * 32 + quad * 8);

  float z2 = 0.f;
#pragma unroll
  for (int j = 0; j < 8; j++) {
    float v = (float)zf[j];
    z2 += v * v;
  }
  z2 += __shfl_xor(z2, 16);
  z2 += __shfl_xor(z2, 32);
  if (quad == 0) z2s[wav * 16 + l15] = z2;

  float best[4] = {1e30f, 1e30f, 1e30f, 1e30f};
  int bidx[4] = {0, 0, 0, 0};

  for (int cb = 0; cb < 2048; cb += 512) {
    __syncthreads();
#pragma unroll
    for (int j = 0; j < 8; j++) {
      int u = j * 256 + tid;
      *(half8*)&Es[u * 8] = *(const half8*)&Eh[(size_t)cb * 32 + u * 8];
    }
    ek2s[tid] = ek2[cb + tid];
    ek2s[tid + 256] = ek2[cb + tid + 256];
    __syncthreads();

    for (int c = 0; c < 512; c += 16) {
      const half8 ef = *(const half8*)&Es[(c + l15) * 32 + quad * 8];
      f32x4 d = (f32x4){0.f, 0.f, 0.f, 0.f};
      d = __builtin_amdgcn_mfma_f32_16x16x32_f16(zf, ef, d, 0, 0, 0);
      const float e2 = ek2s[c + l15];
      const int cg = cb + c + l15;
#pragma unroll
      for (int r = 0; r < 4; r++) {
        float dist = fmaf(-2.f, d[r], e2);
        if (dist < best[r]) { best[r] = dist; bidx[r] = cg; }  // first-min kept
      }
    }
  }

#pragma unroll
  for (int off = 1; off < 16; off <<= 1) {
#pragma unroll
    for (int r = 0; r < 4; r++) {
      float ov = __shfl_xor(best[r], off);
      int oi = __shfl_xor(bidx[r], off);
      if (ov < best[r] || (ov == best[r] && oi < bidx[r])) {
        best[r] = ov;
        bidx[r] = oi;
      }
    }
  }

  float vpart = 0.f;
  if (l15 == 0) {
#pragma unroll
    for (int r = 0; r < 4; r++) {
      idxs[wav * 16 + quad * 4 + r] = bidx[r];
      vpart += z2s[wav * 16 + quad * 4 + r] + best[r];
    }
  }
  vred[tid] = vpart;
  __syncthreads();
  for (int s = 128; s > 0; s >>= 1) {
    if (tid < s) vred[tid] += vred[tid + s];
    __syncthreads();
  }
  if (tid == 0) atomicAdd(vq_acc, vred[0]);

  // gather e rows: 64 rows x 128B fp32, 32B (8 floats) per thread
  const int rowb = tid >> 2, part = tid & 3;
  const int idx = idxs[rowb];
  const size_t orow = ((size_t)blockIdx.x * 64 + rowb) * 32 + part * 8;
  const f32x4 ea = *(const f32x4*)(E + (size_t)idx * 32 + part * 8);
  const f32x4 eb = *(const f32x4*)(E + (size_t)idx * 32 + part * 8 + 4);
  *(f32x4*)(e_out + orow) = ea;
  *(f32x4*)(e_out + orow + 4) = eb;
  half8 ehv;
#pragma unroll
  for (int j = 0; j < 4; j++) { ehv[j] = (_Float16)ea[j]; ehv[j + 4] = (_Float16)eb[j]; }
  *(half8*)(eh_out + orow) = ehv;
}

// W fp32 [K][N] -> Wt fp16 [N][K]
__global__ void transpose_conv(const float* __restrict__ W,
                               _Float16* __restrict__ Wt, int K, int N) {
  __shared__ float t[32][33];
  const int tx = threadIdx.x & 31, ty = threadIdx.x >> 5;
  const int bx = blockIdx.x * 32, by = blockIdx.y * 32;
#pragma unroll
  for (int i = 0; i < 32; i += 8)
    t[ty + i][tx] = W[(size_t)(by + ty + i) * N + bx + tx];
  __syncthreads();
#pragma unroll
  for (int i = 0; i < 32; i += 8)
    Wt[(size_t)(bx + ty + i) * K + by + tx] = (_Float16)t[tx][ty + i];
}

// x fp32 -> fp16, 8 elements/thread
__global__ void conv_x(const float* __restrict__ x, _Float16* __restrict__ xh) {
  const size_t i = (size_t)blockIdx.x * 256 + threadIdx.x;
  const f32x4 a = *(const f32x4*)(x + i * 8);
  const f32x4 b = *(const f32x4*)(x + i * 8 + 4);
  half8 h;
#pragma unroll
  for (int j = 0; j < 4; j++) { h[j] = (_Float16)a[j]; h[j + 4] = (_Float16)b[j]; }
  *(half8*)(xh + i * 8) = h;
}

// E fp32 [2048][32] -> Eh fp16 + per-row squared norms (fp32)
__global__ void conv_E(const float* __restrict__ E, _Float16* __restrict__ Eh,
                       float* __restrict__ ek2) {
  const int c = blockIdx.x * 256 + threadIdx.x;
  float s = 0.f;
#pragma unroll
  for (int k = 0; k < 32; k++) {
    float v = E[(size_t)c * 32 + k];
    s += v * v;
    Eh[(size_t)c * 32 + k] = (_Float16)v;
  }
  ek2[c] = s;
}

__global__ void finalize_k(const float* __restrict__ scal, float* __restrict__ out) {
  const float vq = 1.25f * (scal[0] / 16384.f);  // (1+BETA) * mean
  const float rl = scal[1] / 16384.f;
  out[0] = rl + vq;
  out[1] = rl;
  out[2] = vq;
}

extern "C" void kernel_launch(void* const* d_in, const int* in_sizes, int n_in,
                              void* d_out, int out_size, void* d_ws, size_t ws_size,
                              hipStream_t stream) {
  const float* x = (const float*)d_in[0];
  const float* We1 = (const float*)d_in[1];
  const float* be1 = (const float*)d_in[2];
  const float* We2 = (const float*)d_in[3];
  const float* be2 = (const float*)d_in[4];
  const float* We3 = (const float*)d_in[5];
  const float* be3 = (const float*)d_in[6];
  const float* We4 = (const float*)d_in[7];
  const float* be4 = (const float*)d_in[8];
  const float* E = (const float*)d_in[9];
  const float* Wd1 = (const float*)d_in[10];
  const float* bd1 = (const float*)d_in[11];
  const float* Wd2 = (const float*)d_in[12];
  const float* bd2 = (const float*)d_in[13];
  const float* Wd3 = (const float*)d_in[14];
  const float* bd3 = (const float*)d_in[15];
  const float* Wd4 = (const float*)d_in[16];
  const float* bd4 = (const float*)d_in[17];

  float* out = (float*)d_out;
  char* ws = (char*)d_ws;

  size_t off = 0;
  auto alloc = [&](size_t bytes) {
    size_t r = off;
    off += (bytes + 255) & ~(size_t)255;
    return r;
  };
  const size_t oXH = alloc((size_t)16384 * 1024 * 2);
  const size_t oWT1 = alloc((size_t)1024 * 1024 * 2);
  const size_t oWT2 = alloc((size_t)512 * 1024 * 2);
  const size_t oWT3 = alloc((size_t)256 * 512 * 2);
  const size_t oWT4 = alloc((size_t)256 * 256 * 2);
  const size_t oWD1 = alloc((size_t)256 * 256 * 2);
  const size_t oWD2 = alloc((size_t)512 * 256 * 2);
  const size_t oWD3 = alloc((size_t)1024 * 512 * 2);
  const size_t oWD4 = alloc((size_t)1024 * 1024 * 2);
  const size_t oEH = alloc((size_t)2048 * 32 * 2);
  const size_t oEK2 = alloc((size_t)2048 * 4);
  const size_t oSC = alloc(256);
  const size_t oZH = alloc((size_t)16384 * 256 * 2);
  const size_t oQH = alloc((size_t)16384 * 256 * 2);
  const size_t oH1 = alloc((size_t)16384 * 1024 * 2);  // h1 / d3
  const size_t oH2 = alloc((size_t)16384 * 512 * 2);   // h2 / d2
  const size_t oH3 = alloc((size_t)16384 * 256 * 2);   // h3 / d1

  _Float16* xh = (_Float16*)(ws + oXH);
  _Float16* WT1 = (_Float16*)(ws + oWT1);
  _Float16* WT2 = (_Float16*)(ws + oWT2);
  _Float16* WT3 = (_Float16*)(ws + oWT3);
  _Float16* WT4 = (_Float16*)(ws + oWT4);
  _Float16* WD1 = (_Float16*)(ws + oWD1);
  _Float16* WD2 = (_Float16*)(ws + oWD2);
  _Float16* WD3 = (_Float16*)(ws + oWD3);
  _Float16* WD4 = (_Float16*)(ws + oWD4);
  _Float16* Eh = (_Float16*)(ws + oEH);
  float* ek2 = (float*)(ws + oEK2);
  float* scal = (float*)(ws + oSC);
  _Float16* zhw = (_Float16*)(ws + oZH);
  _Float16* qh = (_Float16*)(ws + oQH);
  _Float16* h1 = (_Float16*)(ws + oH1);
  _Float16* h2 = (_Float16*)(ws + oH2);
  _Float16* h3 = (_Float16*)(ws + oH3);

  float* zout = out;                            // [16384,256]
  float* eout = out + (size_t)16384 * 256;      // [16384,256]
  float* rout = out + (size_t)16384 * 256 * 2;  // [16384,1024]
  float* sout = rout + (size_t)16384 * 1024;    // 3 scalars

  hipMemsetAsync(ws + oSC, 0, 8, stream);

  dim3 blk(256);
  conv_x<<<8192, blk, 0, stream>>>(x, xh);
  transpose_conv<<<dim3(32, 32), blk, 0, stream>>>(We1, WT1, 1024, 1024);
  transpose_conv<<<dim3(16, 32), blk, 0, stream>>>(We2, WT2, 1024, 512);
  transpose_conv<<<dim3(8, 16), blk, 0, stream>>>(We3, WT3, 512, 256);
  transpose_conv<<<dim3(8, 8), blk, 0, stream>>>(We4, WT4, 256, 256);
  transpose_conv<<<dim3(8, 8), blk, 0, stream>>>(Wd1, WD1, 256, 256);
  transpose_conv<<<dim3(16, 8), blk, 0, stream>>>(Wd2, WD2, 256, 512);
  transpose_conv<<<dim3(32, 16), blk, 0, stream>>>(Wd3, WD3, 512, 1024);
  transpose_conv<<<dim3(32, 32), blk, 0, stream>>>(Wd4, WD4, 1024, 1024);
  conv_E<<<8, blk, 0, stream>>>(E, Eh, ek2);

  // encoder
  gemm_bt<0><<<dim3(8, 128), blk, 0, stream>>>(xh, WT1, be1, h1, nullptr, 16384,
                                               1024, 1024, nullptr, nullptr);
  gemm_bt<0><<<dim3(4, 128), blk, 0, stream>>>(h1, WT2, be2, h2, nullptr, 16384,
                                               512, 1024, nullptr, nullptr);
  gemm_bt<0><<<dim3(2, 128), blk, 0, stream>>>(h2, WT3, be3, h3, nullptr, 16384,
                                               256, 512, nullptr, nullptr);
  gemm_bt<1><<<dim3(2, 128), blk, 0, stream>>>(h3, WT4, be4, zhw, zout, 16384,
                                               256, 256, nullptr, nullptr);
  // vector quantizer
  vq_argmin<<<2048, blk, 0, stream>>>(zhw, Eh, E, ek2, eout, qh, &scal[0]);
  // decoder
  gemm_bt<0><<<dim3(2, 128), blk, 0, stream>>>(qh, WD1, bd1, h3, nullptr, 16384,
                                               256, 256, nullptr, nullptr);
  gemm_bt<0><<<dim3(4, 128), blk, 0, stream>>>(h3, WD2, bd2, h2, nullptr, 16384,
                                               512, 256, nullptr, nullptr);
  gemm_bt<0><<<dim3(8, 128), blk, 0, stream>>>(h2, WD3, bd3, h1, nullptr, 16384,
                                               1024, 512, nullptr, nullptr);
  gemm_bt<2><<<dim3(8, 128), blk, 0, stream>>>(h1, WD4, bd4, nullptr, rout, 16384,
                                               1024, 1024, x, &scal[1]);
  finalize_k<<<1, 1, 0, stream>>>(scal, sout);
}

// Round 4
// 468.224 us; speedup vs baseline: 1.1344x; 1.0486x over previous
//
#include <hip/hip_runtime.h>
#include <stdint.h>

typedef __attribute__((ext_vector_type(8))) _Float16 half8;
typedef __attribute__((ext_vector_type(4))) _Float16 half4;
typedef __attribute__((ext_vector_type(4))) float f32x4;

// async global->LDS, 16B per lane; LDS dst must be wave-uniform base + lane*16
__device__ __forceinline__ void gload_lds16(const void* g, void* l) {
  __builtin_amdgcn_global_load_lds(
      (const __attribute__((address_space(1))) void*)g,
      (__attribute__((address_space(3))) void*)l, 16, 0, 0);
}

// C[M,N] = epilogue(A[M,K] @ Bt[N,K]^T + bias)   (A,Bt fp16; bias fp32)
// BK=64, XOR-swizzled LDS staging, coalesced LDS-roundtrip epilogue.
// Tiles: BMxBN with 4 waves in 2x2; BM in {64,128}, BN in {64,128}.
// EPI 0: leaky_relu(0.01) -> Ch fp16
// EPI 1: identity -> Cf fp32 (z out) AND Ch fp16 (z for VQ)
// EPI 2: sigmoid -> Cf fp32 (recon); accumulates sum((sig - Xref)^2) into lossAcc
template <int EPI, int BM, int BN>
__global__ __launch_bounds__(256, (BM == 128 ? 2 : 4)) void gemm_bt(
    const _Float16* __restrict__ A, const _Float16* __restrict__ Bt,
    const float* __restrict__ bias, _Float16* __restrict__ Ch,
    float* __restrict__ Cf, int M, int N, int Kd,
    const float* __restrict__ Xref, float* __restrict__ lossAcc) {
  constexpr int WM = BM / 2, WN = BN / 2;
  constexpr int MF = WM / 16, NF = WN / 16;
  constexpr int CA = BM / 32, CB = BN / 32;   // 16B staging chunks per thread
  constexpr int SMEMH = ((BN * 128) > ((BM + BN) * 64)) ? (BN * 128)
                                                        : ((BM + BN) * 64);
  __shared__ __align__(16) _Float16 smem[SMEMH];
  __shared__ float red[256];
  _Float16* As = smem;
  _Float16* Bs = smem + BM * 64;

  const int tid = threadIdx.x;
  const int lane = tid & 63;
  const int wav = tid >> 6;
  const int m0 = blockIdx.y * BM;
  const int n0 = blockIdx.x * BN;
  const int wm = (wav >> 1) * WM;
  const int wn = (wav & 1) * WN;
  const int l15 = lane & 15;
  const int quad = lane >> 4;

  f32x4 acc[MF][NF];
#pragma unroll
  for (int i = 0; i < MF; i++)
#pragma unroll
    for (int j = 0; j < NF; j++) acc[i][j] = (f32x4){0.f, 0.f, 0.f, 0.f};

  for (int kt = 0; kt < Kd; kt += 64) {
    __syncthreads();
#pragma unroll
    for (int j = 0; j < CA; j++) {
      const int ci = j * 256 + tid;
      const int row = ci >> 3;
      const int kc = ((ci & 7) ^ (row & 7)) << 3;
      gload_lds16(A + (size_t)(m0 + row) * Kd + kt + kc, &As[ci * 8]);
    }
#pragma unroll
    for (int j = 0; j < CB; j++) {
      const int ci = j * 256 + tid;
      const int row = ci >> 3;
      const int kc = ((ci & 7) ^ (row & 7)) << 3;
      gload_lds16(Bt + (size_t)(n0 + row) * Kd + kt + kc, &Bs[ci * 8]);
    }
    __syncthreads();

#pragma unroll
    for (int s = 0; s < 2; s++) {
      half8 af[MF], bq[NF];
#pragma unroll
      for (int i = 0; i < MF; i++) {
        const int ra = wm + i * 16 + l15;
        const int ca = (s * 4 + quad) ^ (ra & 7);
        af[i] = *(const half8*)&As[ra * 64 + ca * 8];
      }
#pragma unroll
      for (int i = 0; i < NF; i++) {
        const int rb = wn + i * 16 + l15;
        const int cb = (s * 4 + quad) ^ (rb & 7);
        bq[i] = *(const half8*)&Bs[rb * 64 + cb * 8];
      }
#pragma unroll
      for (int mi = 0; mi < MF; mi++)
#pragma unroll
        for (int ni = 0; ni < NF; ni++)
          acc[mi][ni] = __builtin_amdgcn_mfma_f32_16x16x32_f16(af[mi], bq[ni],
                                                               acc[mi][ni], 0, 0, 0);
    }
  }

  // epilogue: BM/64 phases of 64 rows through LDS (64 x BN fp32)
  float lsum = 0.f;
  float* eb = (float*)smem;
  constexpr int DIV = BN / 4;  // f32x4 cols
#pragma unroll
  for (int p = 0; p < BM / 64; p++) {
    __syncthreads();
    if ((wm >> 6) == p) {
#pragma unroll
      for (int mi = 0; mi < MF; mi++)
#pragma unroll
        for (int ni = 0; ni < NF; ni++)
#pragma unroll
          for (int r = 0; r < 4; r++) {
            const int rl = (wm & 63) + mi * 16 + quad * 4 + r;
            const int cl = wn + ni * 16 + l15;
            eb[rl * BN + cl] = acc[mi][ni][r];
          }
    }
    __syncthreads();
#pragma unroll
    for (int j = 0; j < BN / 16; j++) {
      const int c = j * 256 + tid;
      const int rl = c / DIV;
      const int cl = (c % DIV) * 4;
      const f32x4 v = *(const f32x4*)&eb[rl * BN + cl];
      const int gcol = n0 + cl;
      const f32x4 bv = *(const f32x4*)&bias[gcol];
      const size_t o = (size_t)(m0 + p * 64 + rl) * N + gcol;
      if (EPI == 0) {
        half4 h;
#pragma unroll
        for (int q = 0; q < 4; q++) {
          float t = v[q] + bv[q];
          t = t > 0.f ? t : 0.01f * t;
          h[q] = (_Float16)t;
        }
        *(half4*)&Ch[o] = h;
      } else if (EPI == 1) {
        f32x4 t;
        half4 h;
#pragma unroll
        for (int q = 0; q < 4; q++) {
          t[q] = v[q] + bv[q];
          h[q] = (_Float16)t[q];
        }
        *(f32x4*)&Cf[o] = t;
        *(half4*)&Ch[o] = h;
      } else {
        const f32x4 xr = *(const f32x4*)&Xref[o];
        f32x4 sv;
#pragma unroll
        for (int q = 0; q < 4; q++) {
          const float s = 1.f / (1.f + __expf(-(v[q] + bv[q])));
          sv[q] = s;
          const float d = s - xr[q];
          lsum += d * d;
        }
        *(f32x4*)&Cf[o] = sv;
      }
    }
  }
  if (EPI == 2) {
    __syncthreads();
    red[tid] = lsum;
    __syncthreads();
    for (int s = 128; s > 0; s >>= 1) {
      if (tid < s) red[tid] += red[tid + s];
      __syncthreads();
    }
    if (tid == 0) atomicAdd(lossAcc, red[0]);
  }
}

// VQ: 128 rows/block, 32 rows/wave. Ehf holds -2*E in MFMA B-fragment order;
// dist = MFMA(z, -2E, C=e2); code index packed into low 11 mantissa bits of
// the fp32 dist key -> min-update is and+or+v_min_f32.
__global__ __launch_bounds__(256, 4) void vq_argmin(
    const _Float16* __restrict__ zh, const _Float16* __restrict__ Ehf,
    const float* __restrict__ E, const float* __restrict__ ek2,
    float* __restrict__ e_out, _Float16* __restrict__ eh_out,
    float* __restrict__ vq_acc) {
  __shared__ __align__(16) _Float16 Es[512 * 32];  // 512 codes, frag order (32 KB)
  __shared__ float ek2s[512];
  __shared__ float z2s[128];
  __shared__ int idxs[128];
  __shared__ float vred[256];

  const int tid = threadIdx.x;
  const int lane = tid & 63;
  const int wav = tid >> 6;
  const int l15 = lane & 15;
  const int quad = lane >> 4;
  const int rbase = blockIdx.x * 128 + wav * 32;
  constexpr unsigned KEYMASK = 0xFFFFF800u;

  half8 zf[2];
  float z2p[2];
#pragma unroll
  for (int m = 0; m < 2; m++) {
    zf[m] = *(const half8*)(zh + ((size_t)(rbase + m * 16 + l15)) * 32 + quad * 8);
    float s = 0.f;
#pragma unroll
    for (int j = 0; j < 8; j++) {
      float v = (float)zf[m][j];
      s += v * v;
    }
    s += __shfl_xor(s, 16);
    s += __shfl_xor(s, 32);
    z2p[m] = s;
  }
  if (quad == 0) {
#pragma unroll
    for (int m = 0; m < 2; m++) z2s[wav * 32 + m * 16 + l15] = z2p[m];
  }

  float key[2][4];
#pragma unroll
  for (int m = 0; m < 2; m++)
#pragma unroll
    for (int r = 0; r < 4; r++) key[m][r] = 1e30f;

  for (int cb = 0; cb < 2048; cb += 512) {
    __syncthreads();
#pragma unroll
    for (int j = 0; j < 8; j++) {
      const int u = j * 256 + tid;
      gload_lds16(Ehf + (size_t)cb * 32 + u * 8, &Es[u * 8]);
    }
    if (tid < 128) gload_lds16(&ek2[cb + tid * 4], &ek2s[tid * 4]);
    __syncthreads();

    int idxv = cb + l15;
    for (int c16 = 0; c16 < 32; c16++) {
      const half8 ef = *(const half8*)&Es[(c16 * 64 + lane) * 8];
      const float e2 = ek2s[c16 * 16 + l15];
      const f32x4 cinit = (f32x4){e2, e2, e2, e2};
      f32x4 d0 = __builtin_amdgcn_mfma_f32_16x16x32_f16(zf[0], ef, cinit, 0, 0, 0);
      f32x4 d1 = __builtin_amdgcn_mfma_f32_16x16x32_f16(zf[1], ef, cinit, 0, 0, 0);
#pragma unroll
      for (int r = 0; r < 4; r++) {
        key[0][r] = fminf(key[0][r],
                          __uint_as_float((__float_as_uint(d0[r]) & KEYMASK) | idxv));
        key[1][r] = fminf(key[1][r],
                          __uint_as_float((__float_as_uint(d1[r]) & KEYMASK) | idxv));
      }
      idxv += 16;
    }
  }

#pragma unroll
  for (int off = 1; off < 16; off <<= 1)
#pragma unroll
    for (int m = 0; m < 2; m++)
#pragma unroll
      for (int r = 0; r < 4; r++)
        key[m][r] = fminf(key[m][r], __shfl_xor(key[m][r], off));

  float vpart = 0.f;
  if (l15 == 0) {
#pragma unroll
    for (int m = 0; m < 2; m++)
#pragma unroll
      for (int r = 0; r < 4; r++) {
        const unsigned kb = __float_as_uint(key[m][r]);
        const int rl = wav * 32 + m * 16 + quad * 4 + r;
        idxs[rl] = (int)(kb & 0x7FFu);
        vpart += z2s[rl] + __uint_as_float(kb & KEYMASK);
      }
  }
  vred[tid] = vpart;
  __syncthreads();
  for (int s = 128; s > 0; s >>= 1) {
    if (tid < s) vred[tid] += vred[tid + s];
    __syncthreads();
  }
  if (tid == 0) atomicAdd(vq_acc, vred[0]);

  // gather e rows: 128 rows x 128B fp32; 4 threads/row, 2 iters
#pragma unroll
  for (int it = 0; it < 2; it++) {
    const int slot = it * 256 + tid;
    const int rowb = slot >> 2, part = slot & 3;
    const int idx = idxs[rowb];
    const size_t orow = ((size_t)blockIdx.x * 128 + rowb) * 32 + part * 8;
    const f32x4 ea = *(const f32x4*)(E + (size_t)idx * 32 + part * 8);
    const f32x4 ebv = *(const f32x4*)(E + (size_t)idx * 32 + part * 8 + 4);
    *(f32x4*)(e_out + orow) = ea;
    *(f32x4*)(e_out + orow + 4) = ebv;
    half8 ehv;
#pragma unroll
    for (int j = 0; j < 4; j++) {
      ehv[j] = (_Float16)ea[j];
      ehv[j + 4] = (_Float16)ebv[j];
    }
    *(half8*)(eh_out + orow) = ehv;
  }
}

// W fp32 [K][N] -> Wt fp16 [N][K]
__global__ void transpose_conv(const float* __restrict__ W,
                               _Float16* __restrict__ Wt, int K, int N) {
  __shared__ float t[32][33];
  const int tx = threadIdx.x & 31, ty = threadIdx.x >> 5;
  const int bx = blockIdx.x * 32, by = blockIdx.y * 32;
#pragma unroll
  for (int i = 0; i < 32; i += 8)
    t[ty + i][tx] = W[(size_t)(by + ty + i) * N + bx + tx];
  __syncthreads();
#pragma unroll
  for (int i = 0; i < 32; i += 8)
    Wt[(size_t)(bx + ty + i) * K + by + tx] = (_Float16)t[tx][ty + i];
}

// x fp32 -> fp16, 8 elements/thread
__global__ void conv_x(const float* __restrict__ x, _Float16* __restrict__ xh) {
  const size_t i = (size_t)blockIdx.x * 256 + threadIdx.x;
  const f32x4 a = *(const f32x4*)(x + i * 8);
  const f32x4 b = *(const f32x4*)(x + i * 8 + 4);
  half8 h;
#pragma unroll
  for (int j = 0; j < 4; j++) { h[j] = (_Float16)a[j]; h[j + 4] = (_Float16)b[j]; }
  *(half8*)(xh + i * 8) = h;
}

// E fp32 [2048][32] -> Ehf = -2*E fp16 in MFMA B-fragment order:
// Ehf[((c>>4)*64 + (k>>3)*16 + (c&15))*8 + (k&7)] ; plus ek2[c] = ||E_c||^2
__global__ void conv_E(const float* __restrict__ E, _Float16* __restrict__ Ehf,
                       float* __restrict__ ek2) {
  const int c = blockIdx.x * 256 + threadIdx.x;
  float s = 0.f;
#pragma unroll
  for (int k = 0; k < 32; k++) {
    const float v = E[(size_t)c * 32 + k];
    s += v * v;
    Ehf[(size_t)((c >> 4) * 64 + (k >> 3) * 16 + (c & 15)) * 8 + (k & 7)] =
        (_Float16)(-2.f * v);
  }
  ek2[c] = s;
}

__global__ void finalize_k(const float* __restrict__ scal, float* __restrict__ out) {
  const float vq = 1.25f * (scal[0] / 16384.f);  // (1+BETA) * mean
  const float rl = scal[1] / 16384.f;
  out[0] = rl + vq;
  out[1] = rl;
  out[2] = vq;
}

extern "C" void kernel_launch(void* const* d_in, const int* in_sizes, int n_in,
                              void* d_out, int out_size, void* d_ws, size_t ws_size,
                              hipStream_t stream) {
  const float* x = (const float*)d_in[0];
  const float* We1 = (const float*)d_in[1];
  const float* be1 = (const float*)d_in[2];
  const float* We2 = (const float*)d_in[3];
  const float* be2 = (const float*)d_in[4];
  const float* We3 = (const float*)d_in[5];
  const float* be3 = (const float*)d_in[6];
  const float* We4 = (const float*)d_in[7];
  const float* be4 = (const float*)d_in[8];
  const float* E = (const float*)d_in[9];
  const float* Wd1 = (const float*)d_in[10];
  const float* bd1 = (const float*)d_in[11];
  const float* Wd2 = (const float*)d_in[12];
  const float* bd2 = (const float*)d_in[13];
  const float* Wd3 = (const float*)d_in[14];
  const float* bd3 = (const float*)d_in[15];
  const float* Wd4 = (const float*)d_in[16];
  const float* bd4 = (const float*)d_in[17];

  float* out = (float*)d_out;
  char* ws = (char*)d_ws;

  size_t off = 0;
  auto alloc = [&](size_t bytes) {
    size_t r = off;
    off += (bytes + 255) & ~(size_t)255;
    return r;
  };
  const size_t oXH = alloc((size_t)16384 * 1024 * 2);
  const size_t oWT1 = alloc((size_t)1024 * 1024 * 2);
  const size_t oWT2 = alloc((size_t)512 * 1024 * 2);
  const size_t oWT3 = alloc((size_t)256 * 512 * 2);
  const size_t oWT4 = alloc((size_t)256 * 256 * 2);
  const size_t oWD1 = alloc((size_t)256 * 256 * 2);
  const size_t oWD2 = alloc((size_t)512 * 256 * 2);
  const size_t oWD3 = alloc((size_t)1024 * 512 * 2);
  const size_t oWD4 = alloc((size_t)1024 * 1024 * 2);
  const size_t oEHF = alloc((size_t)2048 * 32 * 2);
  const size_t oEK2 = alloc((size_t)2048 * 4);
  const size_t oSC = alloc(256);
  const size_t oZH = alloc((size_t)16384 * 256 * 2);
  const size_t oQH = alloc((size_t)16384 * 256 * 2);
  const size_t oH1 = alloc((size_t)16384 * 1024 * 2);  // h1 / d3
  const size_t oH2 = alloc((size_t)16384 * 512 * 2);   // h2 / d2
  const size_t oH3 = alloc((size_t)16384 * 256 * 2);   // h3 / d1

  _Float16* xh = (_Float16*)(ws + oXH);
  _Float16* WT1 = (_Float16*)(ws + oWT1);
  _Float16* WT2 = (_Float16*)(ws + oWT2);
  _Float16* WT3 = (_Float16*)(ws + oWT3);
  _Float16* WT4 = (_Float16*)(ws + oWT4);
  _Float16* WD1 = (_Float16*)(ws + oWD1);
  _Float16* WD2 = (_Float16*)(ws + oWD2);
  _Float16* WD3 = (_Float16*)(ws + oWD3);
  _Float16* WD4 = (_Float16*)(ws + oWD4);
  _Float16* Ehf = (_Float16*)(ws + oEHF);
  float* ek2 = (float*)(ws + oEK2);
  float* scal = (float*)(ws + oSC);
  _Float16* zhw = (_Float16*)(ws + oZH);
  _Float16* qh = (_Float16*)(ws + oQH);
  _Float16* h1 = (_Float16*)(ws + oH1);
  _Float16* h2 = (_Float16*)(ws + oH2);
  _Float16* h3 = (_Float16*)(ws + oH3);

  float* zout = out;                            // [16384,256]
  float* eout = out + (size_t)16384 * 256;      // [16384,256]
  float* rout = out + (size_t)16384 * 256 * 2;  // [16384,1024]
  float* sout = rout + (size_t)16384 * 1024;    // 3 scalars

  hipMemsetAsync(ws + oSC, 0, 8, stream);

  dim3 blk(256);
  conv_x<<<8192, blk, 0, stream>>>(x, xh);
  transpose_conv<<<dim3(32, 32), blk, 0, stream>>>(We1, WT1, 1024, 1024);
  transpose_conv<<<dim3(16, 32), blk, 0, stream>>>(We2, WT2, 1024, 512);
  transpose_conv<<<dim3(8, 16), blk, 0, stream>>>(We3, WT3, 512, 256);
  transpose_conv<<<dim3(8, 8), blk, 0, stream>>>(We4, WT4, 256, 256);
  transpose_conv<<<dim3(8, 8), blk, 0, stream>>>(Wd1, WD1, 256, 256);
  transpose_conv<<<dim3(16, 8), blk, 0, stream>>>(Wd2, WD2, 256, 512);
  transpose_conv<<<dim3(32, 16), blk, 0, stream>>>(Wd3, WD3, 512, 1024);
  transpose_conv<<<dim3(32, 32), blk, 0, stream>>>(Wd4, WD4, 1024, 1024);
  conv_E<<<8, blk, 0, stream>>>(E, Ehf, ek2);

  // encoder
  gemm_bt<0, 64, 128><<<dim3(8, 256), blk, 0, stream>>>(
      xh, WT1, be1, h1, nullptr, 16384, 1024, 1024, nullptr, nullptr);
  gemm_bt<0, 64, 64><<<dim3(8, 256), blk, 0, stream>>>(
      h1, WT2, be2, h2, nullptr, 16384, 512, 1024, nullptr, nullptr);
  gemm_bt<0, 64, 64><<<dim3(4, 256), blk, 0, stream>>>(
      h2, WT3, be3, h3, nullptr, 16384, 256, 512, nullptr, nullptr);
  gemm_bt<1, 64, 64><<<dim3(4, 256), blk, 0, stream>>>(
      h3, WT4, be4, zhw, zout, 16384, 256, 256, nullptr, nullptr);
  // vector quantizer
  vq_argmin<<<1024, blk, 0, stream>>>(zhw, Ehf, E, ek2, eout, qh, &scal[0]);
  // decoder
  gemm_bt<0, 64, 64><<<dim3(4, 256), blk, 0, stream>>>(
      qh, WD1, bd1, h3, nullptr, 16384, 256, 256, nullptr, nullptr);
  gemm_bt<0, 64, 64><<<dim3(8, 256), blk, 0, stream>>>(
      h3, WD2, bd2, h2, nullptr, 16384, 512, 256, nullptr, nullptr);
  gemm_bt<0, 64, 128><<<dim3(8, 256), blk, 0, stream>>>(
      h2, WD3, bd3, h1, nullptr, 16384, 1024, 512, nullptr, nullptr);
  gemm_bt<2, 64, 128><<<dim3(8, 256), blk, 0, stream>>>(
      h1, WD4, bd4, nullptr, rout, 16384, 1024, 1024, x, &scal[1]);
  finalize_k<<<1, 1, 0, stream>>>(scal, sout);
}

// Round 5
// 452.821 us; speedup vs baseline: 1.1730x; 1.0340x over previous
//
#include <hip/hip_runtime.h>
#include <stdint.h>

typedef __attribute__((ext_vector_type(8))) _Float16 half8;
typedef __attribute__((ext_vector_type(4))) _Float16 half4;
typedef __attribute__((ext_vector_type(4))) float f32x4;

// async global->LDS, 16B per lane; LDS dst must be wave-uniform base + lane*16
__device__ __forceinline__ void gload_lds16(const void* g, void* l) {
  __builtin_amdgcn_global_load_lds(
      (const __attribute__((address_space(1))) void*)g,
      (__attribute__((address_space(3))) void*)l, 16, 0, 0);
}

// C[M,N] = epilogue(A[M,K] @ Bt[N,K]^T + bias)   (A,Bt fp16; bias fp32)
// BK=64, XOR-swizzled LDS staging, DOUBLE-BUFFERED with raw s_barrier +
// s_waitcnt vmcnt(CHUNKS): next tile's global_load_lds stays in flight
// through the compute phase (AITER pattern; vmcnt never 0 mid-loop).
// EPI 0: leaky_relu(0.01) -> Ch fp16
// EPI 1: identity -> Cf fp32 (z out) AND Ch fp16 (z for VQ)
// EPI 2: sigmoid -> Cf fp32 (recon); accumulates sum((sig - Xref)^2), Xref fp16
template <int EPI, int BM, int BN>
__global__ __launch_bounds__(256, ((BM + BN) == 192 ? 3 : 4)) void gemm_bt(
    const _Float16* __restrict__ A, const _Float16* __restrict__ Bt,
    const float* __restrict__ bias, _Float16* __restrict__ Ch,
    float* __restrict__ Cf, int M, int N, int Kd,
    const _Float16* __restrict__ Xref, float* __restrict__ lossAcc) {
  constexpr int WM = BM / 2, WN = BN / 2;
  constexpr int MF = WM / 16, NF = WN / 16;
  constexpr int CA = BM / 32, CB = BN / 32;  // 16B staging chunks per thread
  constexpr int CHUNKS = CA + CB;
  constexpr int STAGE = (BM + BN) * 64;  // halfs per buffer
  __shared__ __align__(16) _Float16 smem[2 * STAGE];
  __shared__ float red[256];

  const int tid = threadIdx.x;
  const int lane = tid & 63;
  const int wav = tid >> 6;
  const int m0 = blockIdx.y * BM;
  const int n0 = blockIdx.x * BN;
  const int wm = (wav >> 1) * WM;
  const int wn = (wav & 1) * WN;
  const int l15 = lane & 15;
  const int quad = lane >> 4;

  f32x4 acc[MF][NF];
#pragma unroll
  for (int i = 0; i < MF; i++)
#pragma unroll
    for (int j = 0; j < NF; j++) acc[i][j] = (f32x4){0.f, 0.f, 0.f, 0.f};

  auto issue = [&](int kt, int b) {
    _Float16* As = smem + b * STAGE;
    _Float16* Bs = As + BM * 64;
#pragma unroll
    for (int j = 0; j < CA; j++) {
      const int ci = j * 256 + tid;
      const int row = ci >> 3;
      const int kc = ((ci & 7) ^ (row & 7)) << 3;
      gload_lds16(A + (size_t)(m0 + row) * Kd + kt + kc, &As[ci * 8]);
    }
#pragma unroll
    for (int j = 0; j < CB; j++) {
      const int ci = j * 256 + tid;
      const int row = ci >> 3;
      const int kc = ((ci & 7) ^ (row & 7)) << 3;
      gload_lds16(Bt + (size_t)(n0 + row) * Kd + kt + kc, &Bs[ci * 8]);
    }
  };

  int buf = 0;
  issue(0, 0);
  for (int kt = 0; kt < Kd; kt += 64) {
    if (kt + 64 < Kd) {
      issue(kt + 64, buf ^ 1);
      asm volatile("s_waitcnt vmcnt(%0)" ::"i"(CHUNKS) : "memory");
    } else {
      asm volatile("s_waitcnt vmcnt(0)" ::: "memory");
    }
    asm volatile("s_barrier" ::: "memory");

    const _Float16* As = smem + buf * STAGE;
    const _Float16* Bs = As + BM * 64;
#pragma unroll
    for (int s = 0; s < 2; s++) {
      half8 af[MF], bq[NF];
#pragma unroll
      for (int i = 0; i < MF; i++) {
        const int ra = wm + i * 16 + l15;
        const int ca = (s * 4 + quad) ^ (ra & 7);
        af[i] = *(const half8*)&As[ra * 64 + ca * 8];
      }
#pragma unroll
      for (int i = 0; i < NF; i++) {
        const int rb = wn + i * 16 + l15;
        const int cb = (s * 4 + quad) ^ (rb & 7);
        bq[i] = *(const half8*)&Bs[rb * 64 + cb * 8];
      }
#pragma unroll
      for (int mi = 0; mi < MF; mi++)
#pragma unroll
        for (int ni = 0; ni < NF; ni++)
          acc[mi][ni] = __builtin_amdgcn_mfma_f32_16x16x32_f16(af[mi], bq[ni],
                                                               acc[mi][ni], 0, 0, 0);
    }
    asm volatile("s_barrier" ::: "memory");  // protect buf^1 from next DMA
    buf ^= 1;
  }

  // epilogue: BM/64 phases of 64 rows through LDS (64 x BN fp32)
  float lsum = 0.f;
  float* eb = (float*)smem;
  constexpr int DIV = BN / 4;  // f32x4 cols
#pragma unroll
  for (int p = 0; p < BM / 64; p++) {
    __syncthreads();
    if ((wm >> 6) == p) {
#pragma unroll
      for (int mi = 0; mi < MF; mi++)
#pragma unroll
        for (int ni = 0; ni < NF; ni++)
#pragma unroll
          for (int r = 0; r < 4; r++) {
            const int rl = (wm & 63) + mi * 16 + quad * 4 + r;
            const int cl = wn + ni * 16 + l15;
            eb[rl * BN + cl] = acc[mi][ni][r];
          }
    }
    __syncthreads();
#pragma unroll
    for (int j = 0; j < BN / 16; j++) {
      const int c = j * 256 + tid;
      const int rl = c / DIV;
      const int cl = (c % DIV) * 4;
      const f32x4 v = *(const f32x4*)&eb[rl * BN + cl];
      const int gcol = n0 + cl;
      const f32x4 bv = *(const f32x4*)&bias[gcol];
      const size_t o = (size_t)(m0 + p * 64 + rl) * N + gcol;
      if (EPI == 0) {
        half4 h;
#pragma unroll
        for (int q = 0; q < 4; q++) {
          float t = v[q] + bv[q];
          t = t > 0.f ? t : 0.01f * t;
          h[q] = (_Float16)t;
        }
        *(half4*)&Ch[o] = h;
      } else if (EPI == 1) {
        f32x4 t;
        half4 h;
#pragma unroll
        for (int q = 0; q < 4; q++) {
          t[q] = v[q] + bv[q];
          h[q] = (_Float16)t[q];
        }
        *(f32x4*)&Cf[o] = t;
        *(half4*)&Ch[o] = h;
      } else {
        const half4 xr = *(const half4*)&Xref[o];
        f32x4 sv;
#pragma unroll
        for (int q = 0; q < 4; q++) {
          const float s = 1.f / (1.f + __expf(-(v[q] + bv[q])));
          sv[q] = s;
          const float d = s - (float)xr[q];
          lsum += d * d;
        }
        *(f32x4*)&Cf[o] = sv;
      }
    }
  }
  if (EPI == 2) {
    __syncthreads();
    red[tid] = lsum;
    __syncthreads();
    for (int s = 128; s > 0; s >>= 1) {
      if (tid < s) red[tid] += red[tid + s];
      __syncthreads();
    }
    if (tid == 0) atomicAdd(lossAcc, red[0]);
  }
}

// VQ: 128 rows/block, 32 rows/wave. Ehf holds -2*E in MFMA B-fragment order;
// dist = MFMA(z, -2E, C=e2); code index packed into low 11 mantissa bits of
// the fp32 dist key -> min-update is and+or+v_min_f32.
__global__ __launch_bounds__(256, 4) void vq_argmin(
    const _Float16* __restrict__ zh, const _Float16* __restrict__ Ehf,
    const float* __restrict__ E, const float* __restrict__ ek2,
    float* __restrict__ e_out, _Float16* __restrict__ eh_out,
    float* __restrict__ vq_acc) {
  __shared__ __align__(16) _Float16 Es[512 * 32];  // 512 codes, frag order (32 KB)
  __shared__ float ek2s[512];
  __shared__ float z2s[128];
  __shared__ int idxs[128];
  __shared__ float vred[256];

  const int tid = threadIdx.x;
  const int lane = tid & 63;
  const int wav = tid >> 6;
  const int l15 = lane & 15;
  const int quad = lane >> 4;
  const int rbase = blockIdx.x * 128 + wav * 32;
  constexpr unsigned KEYMASK = 0xFFFFF800u;

  half8 zf[2];
  float z2p[2];
#pragma unroll
  for (int m = 0; m < 2; m++) {
    zf[m] = *(const half8*)(zh + ((size_t)(rbase + m * 16 + l15)) * 32 + quad * 8);
    float s = 0.f;
#pragma unroll
    for (int j = 0; j < 8; j++) {
      float v = (float)zf[m][j];
      s += v * v;
    }
    s += __shfl_xor(s, 16);
    s += __shfl_xor(s, 32);
    z2p[m] = s;
  }
  if (quad == 0) {
#pragma unroll
    for (int m = 0; m < 2; m++) z2s[wav * 32 + m * 16 + l15] = z2p[m];
  }

  float key[2][4];
#pragma unroll
  for (int m = 0; m < 2; m++)
#pragma unroll
    for (int r = 0; r < 4; r++) key[m][r] = 1e30f;

  for (int cb = 0; cb < 2048; cb += 512) {
    __syncthreads();
#pragma unroll
    for (int j = 0; j < 8; j++) {
      const int u = j * 256 + tid;
      gload_lds16(Ehf + (size_t)cb * 32 + u * 8, &Es[u * 8]);
    }
    if (tid < 128) gload_lds16(&ek2[cb + tid * 4], &ek2s[tid * 4]);
    __syncthreads();

    int idxv = cb + l15;
    for (int c16 = 0; c16 < 32; c16++) {
      const half8 ef = *(const half8*)&Es[(c16 * 64 + lane) * 8];
      const float e2 = ek2s[c16 * 16 + l15];
      const f32x4 cinit = (f32x4){e2, e2, e2, e2};
      f32x4 d0 = __builtin_amdgcn_mfma_f32_16x16x32_f16(zf[0], ef, cinit, 0, 0, 0);
      f32x4 d1 = __builtin_amdgcn_mfma_f32_16x16x32_f16(zf[1], ef, cinit, 0, 0, 0);
#pragma unroll
      for (int r = 0; r < 4; r++) {
        key[0][r] = fminf(key[0][r],
                          __uint_as_float((__float_as_uint(d0[r]) & KEYMASK) | idxv));
        key[1][r] = fminf(key[1][r],
                          __uint_as_float((__float_as_uint(d1[r]) & KEYMASK) | idxv));
      }
      idxv += 16;
    }
  }

#pragma unroll
  for (int off = 1; off < 16; off <<= 1)
#pragma unroll
    for (int m = 0; m < 2; m++)
#pragma unroll
      for (int r = 0; r < 4; r++)
        key[m][r] = fminf(key[m][r], __shfl_xor(key[m][r], off));

  float vpart = 0.f;
  if (l15 == 0) {
#pragma unroll
    for (int m = 0; m < 2; m++)
#pragma unroll
      for (int r = 0; r < 4; r++) {
        const unsigned kb = __float_as_uint(key[m][r]);
        const int rl = wav * 32 + m * 16 + quad * 4 + r;
        idxs[rl] = (int)(kb & 0x7FFu);
        vpart += z2s[rl] + __uint_as_float(kb & KEYMASK);
      }
  }
  vred[tid] = vpart;
  __syncthreads();
  for (int s = 128; s > 0; s >>= 1) {
    if (tid < s) vred[tid] += vred[tid + s];
    __syncthreads();
  }
  if (tid == 0) atomicAdd(vq_acc, vred[0]);

  // gather e rows: 128 rows x 128B fp32; 4 threads/row, 2 iters
#pragma unroll
  for (int it = 0; it < 2; it++) {
    const int slot = it * 256 + tid;
    const int rowb = slot >> 2, part = slot & 3;
    const int idx = idxs[rowb];
    const size_t orow = ((size_t)blockIdx.x * 128 + rowb) * 32 + part * 8;
    const f32x4 ea = *(const f32x4*)(E + (size_t)idx * 32 + part * 8);
    const f32x4 ebv = *(const f32x4*)(E + (size_t)idx * 32 + part * 8 + 4);
    *(f32x4*)(e_out + orow) = ea;
    *(f32x4*)(e_out + orow + 4) = ebv;
    half8 ehv;
#pragma unroll
    for (int j = 0; j < 4; j++) {
      ehv[j] = (_Float16)ea[j];
      ehv[j + 4] = (_Float16)ebv[j];
    }
    *(half8*)(eh_out + orow) = ehv;
  }
}

// Fused preprocessing: conv_x (blocks [0,8192)) | 8 weight transposes
// ([8192, 8192+3456)) | conv_E (last 8 blocks).
struct PrepArgs {
  const float* W[8];
  _Float16* Wt[8];
  int Kw[8], Nw[8];
  int base[9];
  const float* x;
  _Float16* xh;
  const float* E;
  _Float16* Ehf;
  float* ek2;
};

__global__ __launch_bounds__(256) void prep_k(PrepArgs a) {
  __shared__ float t[32][33];
  const int b = blockIdx.x;
  const int tid = threadIdx.x;
  if (b < 8192) {  // x fp32 -> fp16, 8 elements/thread
    const size_t i = (size_t)b * 256 + tid;
    const f32x4 va = *(const f32x4*)(a.x + i * 8);
    const f32x4 vb = *(const f32x4*)(a.x + i * 8 + 4);
    half8 h;
#pragma unroll
    for (int j = 0; j < 4; j++) {
      h[j] = (_Float16)va[j];
      h[j + 4] = (_Float16)vb[j];
    }
    *(half8*)(a.xh + i * 8) = h;
    return;
  }
  if (b < 8192 + 3456) {  // W fp32 [K][N] -> Wt fp16 [N][K]
    int l = b - 8192;
    int w = 0;
    while (l >= a.base[w + 1]) w++;
    l -= a.base[w];
    const float* W = a.W[w];
    _Float16* Wt = a.Wt[w];
    const int K = a.Kw[w], N = a.Nw[w];
    const int nb = N >> 5;
    const int bx = (l % nb) * 32, by = (l / nb) * 32;
    const int tx = tid & 31, ty = tid >> 5;
#pragma unroll
    for (int i = 0; i < 32; i += 8)
      t[ty + i][tx] = W[(size_t)(by + ty + i) * N + bx + tx];
    __syncthreads();
#pragma unroll
    for (int i = 0; i < 32; i += 8)
      Wt[(size_t)(bx + ty + i) * K + by + tx] = (_Float16)t[tx][ty + i];
    return;
  }
  // conv_E: Ehf = -2*E fp16 in MFMA B-frag order + ek2 = ||E_c||^2
  const int c = (b - 8192 - 3456) * 256 + tid;
  float s = 0.f;
#pragma unroll
  for (int k = 0; k < 32; k++) {
    const float v = a.E[(size_t)c * 32 + k];
    s += v * v;
    a.Ehf[(size_t)((c >> 4) * 64 + (k >> 3) * 16 + (c & 15)) * 8 + (k & 7)] =
        (_Float16)(-2.f * v);
  }
  a.ek2[c] = s;
}

__global__ void finalize_k(const float* __restrict__ scal, float* __restrict__ out) {
  const float vq = 1.25f * (scal[0] / 16384.f);  // (1+BETA) * mean
  const float rl = scal[1] / 16384.f;
  out[0] = rl + vq;
  out[1] = rl;
  out[2] = vq;
}

extern "C" void kernel_launch(void* const* d_in, const int* in_sizes, int n_in,
                              void* d_out, int out_size, void* d_ws, size_t ws_size,
                              hipStream_t stream) {
  const float* x = (const float*)d_in[0];
  const float* be1 = (const float*)d_in[2];
  const float* be2 = (const float*)d_in[4];
  const float* be3 = (const float*)d_in[6];
  const float* be4 = (const float*)d_in[8];
  const float* E = (const float*)d_in[9];
  const float* bd1 = (const float*)d_in[11];
  const float* bd2 = (const float*)d_in[13];
  const float* bd3 = (const float*)d_in[15];
  const float* bd4 = (const float*)d_in[17];

  float* out = (float*)d_out;
  char* ws = (char*)d_ws;

  size_t off = 0;
  auto alloc = [&](size_t bytes) {
    size_t r = off;
    off += (bytes + 255) & ~(size_t)255;
    return r;
  };
  const size_t oXH = alloc((size_t)16384 * 1024 * 2);
  const size_t oWT1 = alloc((size_t)1024 * 1024 * 2);
  const size_t oWT2 = alloc((size_t)512 * 1024 * 2);
  const size_t oWT3 = alloc((size_t)256 * 512 * 2);
  const size_t oWT4 = alloc((size_t)256 * 256 * 2);
  const size_t oWD1 = alloc((size_t)256 * 256 * 2);
  const size_t oWD2 = alloc((size_t)512 * 256 * 2);
  const size_t oWD3 = alloc((size_t)1024 * 512 * 2);
  const size_t oWD4 = alloc((size_t)1024 * 1024 * 2);
  const size_t oEHF = alloc((size_t)2048 * 32 * 2);
  const size_t oEK2 = alloc((size_t)2048 * 4);
  const size_t oSC = alloc(256);
  const size_t oZH = alloc((size_t)16384 * 256 * 2);
  const size_t oQH = alloc((size_t)16384 * 256 * 2);
  const size_t oH1 = alloc((size_t)16384 * 1024 * 2);  // h1 / d3
  const size_t oH2 = alloc((size_t)16384 * 512 * 2);   // h2 / d2
  const size_t oH3 = alloc((size_t)16384 * 256 * 2);   // h3 / d1

  _Float16* xh = (_Float16*)(ws + oXH);
  _Float16* WT1 = (_Float16*)(ws + oWT1);
  _Float16* WT2 = (_Float16*)(ws + oWT2);
  _Float16* WT3 = (_Float16*)(ws + oWT3);
  _Float16* WT4 = (_Float16*)(ws + oWT4);
  _Float16* WD1 = (_Float16*)(ws + oWD1);
  _Float16* WD2 = (_Float16*)(ws + oWD2);
  _Float16* WD3 = (_Float16*)(ws + oWD3);
  _Float16* WD4 = (_Float16*)(ws + oWD4);
  _Float16* Ehf = (_Float16*)(ws + oEHF);
  float* ek2 = (float*)(ws + oEK2);
  float* scal = (float*)(ws + oSC);
  _Float16* zhw = (_Float16*)(ws + oZH);
  _Float16* qh = (_Float16*)(ws + oQH);
  _Float16* h1 = (_Float16*)(ws + oH1);
  _Float16* h2 = (_Float16*)(ws + oH2);
  _Float16* h3 = (_Float16*)(ws + oH3);

  float* zout = out;                            // [16384,256]
  float* eout = out + (size_t)16384 * 256;      // [16384,256]
  float* rout = out + (size_t)16384 * 256 * 2;  // [16384,1024]
  float* sout = rout + (size_t)16384 * 1024;    // 3 scalars

  hipMemsetAsync(ws + oSC, 0, 8, stream);

  PrepArgs pa;
  pa.W[0] = (const float*)d_in[1];  pa.Wt[0] = WT1; pa.Kw[0] = 1024; pa.Nw[0] = 1024;
  pa.W[1] = (const float*)d_in[3];  pa.Wt[1] = WT2; pa.Kw[1] = 1024; pa.Nw[1] = 512;
  pa.W[2] = (const float*)d_in[5];  pa.Wt[2] = WT3; pa.Kw[2] = 512;  pa.Nw[2] = 256;
  pa.W[3] = (const float*)d_in[7];  pa.Wt[3] = WT4; pa.Kw[3] = 256;  pa.Nw[3] = 256;
  pa.W[4] = (const float*)d_in[10]; pa.Wt[4] = WD1; pa.Kw[4] = 256;  pa.Nw[4] = 256;
  pa.W[5] = (const float*)d_in[12]; pa.Wt[5] = WD2; pa.Kw[5] = 256;  pa.Nw[5] = 512;
  pa.W[6] = (const float*)d_in[14]; pa.Wt[6] = WD3; pa.Kw[6] = 512;  pa.Nw[6] = 1024;
  pa.W[7] = (const float*)d_in[16]; pa.Wt[7] = WD4; pa.Kw[7] = 1024; pa.Nw[7] = 1024;
  int acc = 0;
  for (int w = 0; w < 8; w++) {
    pa.base[w] = acc;
    acc += (pa.Kw[w] >> 5) * (pa.Nw[w] >> 5);
  }
  pa.base[8] = acc;  // 3456
  pa.x = x; pa.xh = xh; pa.E = E; pa.Ehf = Ehf; pa.ek2 = ek2;

  dim3 blk(256);
  prep_k<<<8192 + 3456 + 8, blk, 0, stream>>>(pa);

  // encoder
  gemm_bt<0, 64, 128><<<dim3(8, 256), blk, 0, stream>>>(
      xh, WT1, be1, h1, nullptr, 16384, 1024, 1024, nullptr, nullptr);
  gemm_bt<0, 64, 128><<<dim3(4, 256), blk, 0, stream>>>(
      h1, WT2, be2, h2, nullptr, 16384, 512, 1024, nullptr, nullptr);
  gemm_bt<0, 64, 64><<<dim3(4, 256), blk, 0, stream>>>(
      h2, WT3, be3, h3, nullptr, 16384, 256, 512, nullptr, nullptr);
  gemm_bt<1, 64, 64><<<dim3(4, 256), blk, 0, stream>>>(
      h3, WT4, be4, zhw, zout, 16384, 256, 256, nullptr, nullptr);
  // vector quantizer
  vq_argmin<<<1024, blk, 0, stream>>>(zhw, Ehf, E, ek2, eout, qh, &scal[0]);
  // decoder
  gemm_bt<0, 64, 64><<<dim3(4, 256), blk, 0, stream>>>(
      qh, WD1, bd1, h3, nullptr, 16384, 256, 256, nullptr, nullptr);
  gemm_bt<0, 64, 128><<<dim3(4, 256), blk, 0, stream>>>(
      h3, WD2, bd2, h2, nullptr, 16384, 512, 256, nullptr, nullptr);
  gemm_bt<0, 64, 128><<<dim3(8, 256), blk, 0, stream>>>(
      h2, WD3, bd3, h1, nullptr, 16384, 1024, 512, nullptr, nullptr);
  gemm_bt<2, 64, 128><<<dim3(8, 256), blk, 0, stream>>>(
      h1, WD4, bd4, nullptr, rout, 16384, 1024, 1024, xh, &scal[1]);
  finalize_k<<<1, 1, 0, stream>>>(scal, sout);
}